// Round 10
// baseline (411.391 us; speedup 1.0000x reference)
//
#include <hip/hip_runtime.h>
#include <hip/hip_bf16.h>
#include <math.h>

#define H 128
#define BKT_SHIFT 9
#define BKT_NODES 512
#define CHUNK 2048   // edges per block in phase A/B
#define GEMM_GRID 512
#define FP8_SCALE 64.0f
#define FP8_INV (1.0f / 64.0f)

typedef __attribute__((ext_vector_type(8))) short short8;
typedef __attribute__((ext_vector_type(4))) float f32x4;
typedef __attribute__((ext_vector_type(2))) float f32x2;

static __device__ __forceinline__ ushort f2b(float v) {
    union { float f; unsigned u; } x; x.f = v;
    unsigned r = x.u + 0x7fffu + ((x.u >> 16) & 1u);
    return (ushort)(r >> 16);
}

// ---------------- Bucketed CSR build ----------------

__global__ void bucket_hist_kernel(const int* __restrict__ dst, int e,
                                   int* __restrict__ bucketCount, int* __restrict__ blockBase) {
    __shared__ int hist[256];
    int t = threadIdx.x;
    hist[t] = 0;
    __syncthreads();
    int base = blockIdx.x * CHUNK;
    #pragma unroll
    for (int k = 0; k < CHUNK / 256; k++) {
        int i = base + k * 256 + t;
        if (i < e) atomicAdd(&hist[dst[i] >> BKT_SHIFT], 1);
    }
    __syncthreads();
    blockBase[blockIdx.x * 256 + t] = atomicAdd(&bucketCount[t], hist[t]);
}

__global__ void bucket_scan_kernel(const int* __restrict__ bucketCount, int* __restrict__ bucketBase,
                                   int* __restrict__ rs, int n, int e) {
    if (threadIdx.x == 0 && blockIdx.x == 0) {
        int acc = 0;
        for (int i = 0; i < 256; i++) { bucketBase[i] = acc; acc += bucketCount[i]; }
        bucketBase[256] = acc;
        rs[n] = e;
    }
}

__global__ void bucket_scatter_kernel(const int* __restrict__ src, const int* __restrict__ dst, int e,
                                      const int* __restrict__ bucketBase, const int* __restrict__ blockBase,
                                      int2* __restrict__ grouped) {
    __shared__ int cur[256];
    int t = threadIdx.x;
    cur[t] = bucketBase[t] + blockBase[blockIdx.x * 256 + t];
    __syncthreads();
    int base = blockIdx.x * CHUNK;
    #pragma unroll
    for (int k = 0; k < CHUNK / 256; k++) {
        int i = base + k * 256 + t;
        if (i < e) {
            int d = dst[i];
            int pos = atomicAdd(&cur[d >> BKT_SHIFT], 1);
            int2 p; p.x = d; p.y = src[i];
            grouped[pos] = p;
        }
    }
}

__global__ void bucket_csr_kernel(const int2* __restrict__ grouped, const int* __restrict__ bucketBase,
                                  int* __restrict__ rs, int* __restrict__ csr, int n) {
    __shared__ int sdeg[BKT_NODES];
    __shared__ int sexcl[BKT_NODES];
    __shared__ int wsum[4];
    int b = blockIdx.x;
    int t = threadIdx.x;
    int nodeBase = b << BKT_SHIFT;
    int ebase = bucketBase[b], eend = bucketBase[b + 1];
    sdeg[t] = 0; sdeg[t + 256] = 0;
    __syncthreads();
    for (int e = ebase + t; e < eend; e += 256)
        atomicAdd(&sdeg[grouped[e].x - nodeBase], 1);
    __syncthreads();
    int lane = t & 63, wid = t >> 6;
    int v0 = sdeg[2 * t], v1 = sdeg[2 * t + 1];
    int p = v0 + v1;
    int x = p;
    #pragma unroll
    for (int off = 1; off < 64; off <<= 1) {
        int y = __shfl_up(x, off, 64);
        if (lane >= off) x += y;
    }
    if (lane == 63) wsum[wid] = x;
    __syncthreads();
    if (t == 0) {
        int acc = 0;
        #pragma unroll
        for (int w = 0; w < 4; w++) { int tmp = wsum[w]; wsum[w] = acc; acc += tmp; }
    }
    __syncthreads();
    int basep = wsum[wid] + x - p;
    sexcl[2 * t] = basep;
    sexcl[2 * t + 1] = basep + v0;
    int nodes = min(BKT_NODES, n - nodeBase);
    for (int i = t; i < nodes; i += 256) rs[nodeBase + i] = ebase + sexcl[i];
    sdeg[t] = 0; sdeg[t + 256] = 0;
    __syncthreads();
    for (int e = ebase + t; e < eend; e += 256) {
        int2 pr = grouped[e];
        int l = pr.x - nodeBase;
        int r = atomicAdd(&sdeg[l], 1);
        csr[ebase + sexcl[l] + r] = pr.y;
    }
}

// ---------------- Weight prep: Btg[layer][col][k] bf16, k<128 Wl, k>=128 Wr ----------------

__global__ void prep_w_kernel(const float* __restrict__ Wl, const float* __restrict__ Wr,
                              ushort* __restrict__ Btg) {
    int idx = blockIdx.x * 256 + threadIdx.x;   // 2*128*256 = 65536
    if (idx >= 65536) return;
    int l = idx >> 15;
    int col = (idx >> 8) & 127;
    int k = idx & 255;
    float v = (k < 128) ? Wl[l * H * H + k * H + col] : Wr[l * H * H + (k - 128) * H + col];
    Btg[idx] = f2b(v);
}

// ---------------- Layer 0 (in_dim = 1) ----------------

__global__ void agg0_kernel(const float* __restrict__ x, const int* __restrict__ rs,
                            const int* __restrict__ csr, float* __restrict__ agg0, int n) {
    int i = blockIdx.x * 256 + threadIdx.x;
    if (i >= n) return;
    int a = rs[i], b = rs[i + 1];
    float s = 0.f;
    for (int e = a; e < b; e++) s += x[csr[e]];
    agg0[i] = s / (float)max(b - a, 1);
}

// thread = (node, plane of 32 features): bf16 row-major + fp8 plane-major [4][N][32]
__global__ void expand0_kernel(const float* __restrict__ x, const float* __restrict__ agg0,
                               const float* __restrict__ Wl0, const float* __restrict__ bl0,
                               const float* __restrict__ Wr0, ushort* __restrict__ hout,
                               unsigned char* __restrict__ h8, int n) {
    int idx = blockIdx.x * 256 + threadIdx.x;   // over N*4
    if (idx >= n * 4) return;
    int i = idx >> 2, p = idx & 3;
    float gi = agg0[i], xi = x[i];
    float v[32];
    #pragma unroll
    for (int k = 0; k < 32; k++) {
        int f = p * 32 + k;
        v[k] = fmaxf(gi * Wl0[f] + bl0[f] + xi * Wr0[f], 0.f);
    }
    ushort* hp = hout + (size_t)i * H + p * 32;
    #pragma unroll
    for (int q = 0; q < 4; q++) {
        short8 o;
        #pragma unroll
        for (int k = 0; k < 8; k++) o[k] = (short)f2b(v[q * 8 + k]);
        *(short8*)(hp + q * 8) = o;
    }
    unsigned up[8];
    #pragma unroll
    for (int d = 0; d < 8; d++) {
        int pk = __builtin_amdgcn_cvt_pk_fp8_f32(v[4 * d] * FP8_SCALE, v[4 * d + 1] * FP8_SCALE, 0, false);
        pk = __builtin_amdgcn_cvt_pk_fp8_f32(v[4 * d + 2] * FP8_SCALE, v[4 * d + 3] * FP8_SCALE, pk, true);
        up[d] = (unsigned)pk;
    }
    unsigned char* dst8 = h8 + ((size_t)p * n + i) * 32;
    *(uint4*)dst8 = (uint4){up[0], up[1], up[2], up[3]};
    *(uint4*)(dst8 + 16) = (uint4){up[4], up[5], up[6], up[7]};
}

// ---------------- Plane-partitioned aggregate, wave-parallel ----------------
// plane = blockIdx&3 -> 3.2 MB plane per XCD L2 (de-facto %8 block->XCD round-robin).
// Wave per (node, plane): 8 slots x 8 lanes x 4B -> 8 neighbors in flight, 32B/row coalesced.

__global__ void aggregate_p_kernel(const unsigned char* __restrict__ h8, const int* __restrict__ rs,
                                   const int* __restrict__ csr, ushort* __restrict__ aggp, int n) {
    int plane = blockIdx.x & 3;
    int node = (blockIdx.x >> 2) * 4 + (threadIdx.x >> 6);
    if (node >= n) return;
    int lane = threadIdx.x & 63;
    int slot = lane >> 3, fl = lane & 7;
    const unsigned char* pb = h8 + (size_t)plane * n * 32;
    int a = rs[node], b = rs[node + 1];
    f32x2 s0 = (f32x2){0.f, 0.f}, s1 = (f32x2){0.f, 0.f};
    int e = a;
    for (; e + 8 <= b; e += 8) {
        int nb = csr[e + slot];
        unsigned u = *(const unsigned*)(pb + (size_t)nb * 32 + fl * 4);
        s0 += __builtin_amdgcn_cvt_pk_f32_fp8(u, false);
        s1 += __builtin_amdgcn_cvt_pk_f32_fp8(u, true);
    }
    if (e + slot < b) {
        int nb = csr[e + slot];
        unsigned u = *(const unsigned*)(pb + (size_t)nb * 32 + fl * 4);
        s0 += __builtin_amdgcn_cvt_pk_f32_fp8(u, false);
        s1 += __builtin_amdgcn_cvt_pk_f32_fp8(u, true);
    }
    #pragma unroll
    for (int m = 8; m < 64; m <<= 1) {
        s0.x += __shfl_xor(s0.x, m, 64);
        s0.y += __shfl_xor(s0.y, m, 64);
        s1.x += __shfl_xor(s1.x, m, 64);
        s1.y += __shfl_xor(s1.y, m, 64);
    }
    if (slot == 0) {
        float inv = FP8_INV / (float)max(b - a, 1);
        ushort4 o;
        o.x = f2b(s0.x * inv); o.y = f2b(s0.y * inv);
        o.z = f2b(s1.x * inv); o.w = f2b(s1.y * inv);
        *(ushort4*)(aggp + ((size_t)plane * n + node) * 32 + fl * 4) = o;
    }
}

// ---------------- Fused dual GEMM, B in registers, transposed MFMA output ----------------
// A: agg half from plane-major bf16 [4][N][32] (aggp), root half from row-major bf16 (hb).
// POOL=false: store bf16 rows + fp8 plane-major shadow. POOL=true: feature sums.

template<bool POOL>
__global__ __launch_bounds__(256, 2) void gemm_kernel(
    const ushort* __restrict__ aggp, const ushort* __restrict__ hb,
    const ushort* __restrict__ Btg,   // [128][256] bf16 for this layer
    const float* __restrict__ bias, ushort* __restrict__ out,
    unsigned char* __restrict__ out8,
    float* __restrict__ partial, int nblk, int n) {
    __shared__ float sums[2][128];
    int tid = threadIdx.x;
    int wave = tid >> 6, lane = tid & 63;
    int l15 = lane & 15, lhi = lane >> 4;
    int colhalf = wave & 1;
    int rowsub = wave >> 1;
    int colbase = colhalf * 64;

    short8 bf[4][8];
    #pragma unroll
    for (int c2 = 0; c2 < 4; c2++) {
        const ushort* wp = Btg + (colbase + c2 * 16 + l15) * 256 + lhi * 8;
        #pragma unroll
        for (int s = 0; s < 8; s++)
            bf[c2][s] = *(const short8*)(wp + s * 32);
    }
    f32x4 bias_v[4];
    #pragma unroll
    for (int c2 = 0; c2 < 4; c2++)
        bias_v[c2] = *(const f32x4*)(bias + colbase + c2 * 16 + lhi * 4);

    f32x4 fs[4];
    #pragma unroll
    for (int c2 = 0; c2 < 4; c2++) fs[c2] = (f32x4){0.f, 0.f, 0.f, 0.f};

    for (int r0 = blockIdx.x * 32; r0 < n; r0 += nblk * 32) {
        int row = r0 + rowsub * 16 + l15;
        int arow = min(row, n - 1);
        short8 af[8];
        #pragma unroll
        for (int s = 0; s < 4; s++)
            af[s] = *(const short8*)(aggp + ((size_t)s * n + arow) * 32 + lhi * 8);
        #pragma unroll
        for (int s = 4; s < 8; s++)
            af[s] = *(const short8*)(hb + (size_t)arow * H + (s & 3) * 32 + lhi * 8);
        f32x4 acc[4];
        #pragma unroll
        for (int c2 = 0; c2 < 4; c2++) acc[c2] = (f32x4){0.f, 0.f, 0.f, 0.f};
        #pragma unroll
        for (int s = 0; s < 8; s++) {
            #pragma unroll
            for (int c2 = 0; c2 < 4; c2++)
                acc[c2] = __builtin_amdgcn_mfma_f32_16x16x32_bf16(bf[c2][s], af[s], acc[c2], 0, 0, 0);
        }
        if (row < n) {
            if (POOL) {
                #pragma unroll
                for (int c2 = 0; c2 < 4; c2++)
                    #pragma unroll
                    for (int r = 0; r < 4; r++)
                        fs[c2][r] += fmaxf(acc[c2][r] + bias_v[c2][r], 0.f);
            } else {
                #pragma unroll
                for (int c2 = 0; c2 < 4; c2++) {
                    float v0 = fmaxf(acc[c2][0] + bias_v[c2][0], 0.f);
                    float v1 = fmaxf(acc[c2][1] + bias_v[c2][1], 0.f);
                    float v2 = fmaxf(acc[c2][2] + bias_v[c2][2], 0.f);
                    float v3 = fmaxf(acc[c2][3] + bias_v[c2][3], 0.f);
                    ushort4 o;
                    o.x = f2b(v0); o.y = f2b(v1); o.z = f2b(v2); o.w = f2b(v3);
                    *(ushort4*)(out + (size_t)row * H + colbase + c2 * 16 + lhi * 4) = o;
                    int pk = __builtin_amdgcn_cvt_pk_fp8_f32(v0 * FP8_SCALE, v1 * FP8_SCALE, 0, false);
                    pk = __builtin_amdgcn_cvt_pk_fp8_f32(v2 * FP8_SCALE, v3 * FP8_SCALE, pk, true);
                    int col0 = colbase + c2 * 16 + lhi * 4;
                    int pl = col0 >> 5;
                    *(unsigned*)(out8 + ((size_t)pl * n + row) * 32 + (col0 & 31)) = (unsigned)pk;
                }
            }
        }
    }

    if (POOL) {
        #pragma unroll
        for (int c2 = 0; c2 < 4; c2++) {
            #pragma unroll
            for (int m = 1; m < 16; m <<= 1) {
                #pragma unroll
                for (int r = 0; r < 4; r++)
                    fs[c2][r] += __shfl_xor(fs[c2][r], m, 64);
            }
        }
        if (l15 == 0) {
            #pragma unroll
            for (int c2 = 0; c2 < 4; c2++)
                #pragma unroll
                for (int r = 0; r < 4; r++)
                    sums[rowsub][colbase + c2 * 16 + lhi * 4 + r] = fs[c2][r];
        }
        __syncthreads();
        if (tid < 128)
            partial[tid * nblk + blockIdx.x] = sums[0][tid] + sums[1][tid];
    }
}

// ---------------- Final pooling reduce: one wave per feature ----------------

__global__ void pool_reduce_kernel(const float* __restrict__ partial, float* __restrict__ pooled,
                                   int nb, float invn) {
    int j = blockIdx.x;
    int t = threadIdx.x;     // 64
    float s = 0.f;
    for (int b = t; b < nb; b += 64) s += partial[j * nb + b];
    #pragma unroll
    for (int off = 32; off > 0; off >>= 1) s += __shfl_down(s, off, 64);
    if (t == 0) pooled[j] = s * invn;
}

// ---------------- Final MLP ----------------

__global__ void mlp_kernel(const float* __restrict__ pooled,
                           const float* __restrict__ Wv, const float* __restrict__ bv,
                           const float* __restrict__ temp, const float* __restrict__ tt,
                           const float* __restrict__ Wm1, const float* __restrict__ bm1,
                           const float* __restrict__ Wm2, const float* __restrict__ bm2,
                           float* __restrict__ out) {
    __shared__ float feat[66];
    __shared__ float red[2];
    int j = threadIdx.x;  // 128 threads
    if (j < 64) {
        float s = bv[j];
        for (int k = 0; k < H; k++) s += pooled[k] * Wv[k * 64 + j];
        feat[j] = s;
    }
    if (j == 64) feat[64] = temp[0];
    if (j == 65) feat[65] = tt[0];
    __syncthreads();
    float m = bm1[j];
    for (int k = 0; k < 66; k++) m += feat[k] * Wm1[k * H + j];
    m = fmaxf(m, 0.f);
    float p = m * Wm2[j];
    #pragma unroll
    for (int off = 32; off > 0; off >>= 1) p += __shfl_down(p, off, 64);
    if ((j & 63) == 0) red[j >> 6] = p;
    __syncthreads();
    if (j == 0) {
        float x = red[0] + red[1] + bm2[0];
        out[0] = (x > 20.f) ? x : log1pf(expf(x));
    }
}

// ---------------- Launch ----------------

extern "C" void kernel_launch(void* const* d_in, const int* in_sizes, int n_in,
                              void* d_out, int out_size, void* d_ws, size_t ws_size,
                              hipStream_t stream) {
    const float* node_feats = (const float*)d_in[0];
    const int* edge_index = (const int*)d_in[1];
    const float* temp = (const float*)d_in[3];
    const float* tt   = (const float*)d_in[4];
    const float* Wl0 = (const float*)d_in[5];
    const float* bl0 = (const float*)d_in[6];
    const float* Wr0 = (const float*)d_in[7];
    const float* Wl  = (const float*)d_in[8];
    const float* bl  = (const float*)d_in[9];
    const float* Wr  = (const float*)d_in[10];
    const float* Wv  = (const float*)d_in[11];
    const float* bv  = (const float*)d_in[12];
    const float* Wm1 = (const float*)d_in[13];
    const float* bm1 = (const float*)d_in[14];
    const float* Wm2 = (const float*)d_in[15];
    const float* bm2 = (const float*)d_in[16];

    const int N = in_sizes[0];
    const int E = in_sizes[1] / 2;
    const int* src = edge_index;
    const int* dst = edge_index + E;

    size_t NH = (size_t)N * H;
    ushort* hA   = (ushort*)d_ws;            // N*H bf16 (row-major)
    ushort* hB   = hA + NH;                  // N*H bf16 (row-major)
    ushort* aggp = hB + NH;                  // N*H bf16 (plane-major [4][N][32])
    ushort* Btg  = aggp + NH;                // 2*128*256 bf16
    float* agg0  = (float*)(Btg + 65536);    // N f32
    int2* grouped = (int2*)(agg0 + N);       // E pairs (dead after CSR build)
    int* csr     = (int*)(grouped + E);      // E
    int* rs      = csr + E;                  // N+1
    int* bucketCount = rs + (N + 1);         // 256
    int* bucketBase  = bucketCount + 256;    // 257
    int* blockBase   = bucketBase + 257;     // NBLK*256
    int NBLK = (E + CHUNK - 1) / CHUNK;
    float* partial = (float*)(blockBase + NBLK * 256);  // H*GEMM_GRID
    float* pooled  = partial + (size_t)H * GEMM_GRID;   // H
    unsigned char* hB8 = (unsigned char*)(pooled + H);  // [4][N][32] fp8
    unsigned char* hA8 = (unsigned char*)grouped;       // [4][N][32] fp8, aliases dead 'grouped'

    int NB = (N + BKT_NODES - 1) / BKT_NODES;

    // CSR build (bucketed)
    hipMemsetAsync(bucketCount, 0, 256 * sizeof(int), stream);
    bucket_hist_kernel<<<NBLK, 256, 0, stream>>>(dst, E, bucketCount, blockBase);
    bucket_scan_kernel<<<1, 64, 0, stream>>>(bucketCount, bucketBase, rs, N, E);
    bucket_scatter_kernel<<<NBLK, 256, 0, stream>>>(src, dst, E, bucketBase, blockBase, grouped);
    bucket_csr_kernel<<<NB, 256, 0, stream>>>(grouped, bucketBase, rs, csr, N);

    // Weights -> bf16 transposed [layer][col][k]
    prep_w_kernel<<<256, 256, 0, stream>>>(Wl, Wr, Btg);

    // Layer 0 scalar part -> hA (bf16 rows) + hA8 (fp8 planes; grouped dead by now)
    agg0_kernel<<<(N + 255) / 256, 256, 0, stream>>>(node_feats, rs, csr, agg0, N);
    expand0_kernel<<<((size_t)N * 4 + 255) / 256, 256, 0, stream>>>(
        node_feats, agg0, Wl0, bl0, Wr0, hA, hA8, N);

    int AGG_GRID = ((N + 3) / 4) * 4;   // node-groups of 4 x 4 planes

    // Layer 1: plane-local fp8 gather-mean on hA8 -> gemm -> hB (+ hB8 planes)
    aggregate_p_kernel<<<AGG_GRID, 256, 0, stream>>>(hA8, rs, csr, aggp, N);
    gemm_kernel<false><<<GEMM_GRID, 256, 0, stream>>>(aggp, hA, Btg, bl, hB, hB8, nullptr, GEMM_GRID, N);

    // Layer 2: plane-local fp8 gather-mean on hB8 -> gemm (fused pooling)
    aggregate_p_kernel<<<AGG_GRID, 256, 0, stream>>>(hB8, rs, csr, aggp, N);
    gemm_kernel<true><<<GEMM_GRID, 256, 0, stream>>>(aggp, hB, Btg + 32768, bl + H, nullptr, nullptr, partial, GEMM_GRID, N);

    // Final pooling reduce + MLP
    pool_reduce_kernel<<<H, 64, 0, stream>>>(partial, pooled, GEMM_GRID, 1.0f / (float)N);
    mlp_kernel<<<1, H, 0, stream>>>(pooled, Wv, bv, temp, tt, Wm1, bm1, Wm2, bm2, (float*)d_out);
}

// Round 11
// 293.371 us; speedup vs baseline: 1.4023x; 1.4023x over previous
//
#include <hip/hip_runtime.h>
#include <hip/hip_bf16.h>
#include <math.h>

#define H 128
#define BKT_SHIFT 9
#define BKT_NODES 512
#define CHUNK 2048   // edges per block in phase A/B
#define GEMM_GRID 512
#define FP8_SCALE 64.0f
#define FP8_INV (1.0f / 64.0f)

typedef __attribute__((ext_vector_type(8))) short short8;
typedef __attribute__((ext_vector_type(4))) float f32x4;
typedef __attribute__((ext_vector_type(2))) float f32x2;

static __device__ __forceinline__ ushort f2b(float v) {
    union { float f; unsigned u; } x; x.f = v;
    unsigned r = x.u + 0x7fffu + ((x.u >> 16) & 1u);
    return (ushort)(r >> 16);
}

// ---------------- Bucketed CSR build ----------------

__global__ void bucket_hist_kernel(const int* __restrict__ dst, int e,
                                   int* __restrict__ bucketCount, int* __restrict__ blockBase) {
    __shared__ int hist[256];
    int t = threadIdx.x;
    hist[t] = 0;
    __syncthreads();
    int base = blockIdx.x * CHUNK;
    #pragma unroll
    for (int k = 0; k < CHUNK / 256; k++) {
        int i = base + k * 256 + t;
        if (i < e) atomicAdd(&hist[dst[i] >> BKT_SHIFT], 1);
    }
    __syncthreads();
    blockBase[blockIdx.x * 256 + t] = atomicAdd(&bucketCount[t], hist[t]);
}

__global__ void bucket_scan_kernel(const int* __restrict__ bucketCount, int* __restrict__ bucketBase,
                                   int* __restrict__ rs, int n, int e) {
    if (threadIdx.x == 0 && blockIdx.x == 0) {
        int acc = 0;
        for (int i = 0; i < 256; i++) { bucketBase[i] = acc; acc += bucketCount[i]; }
        bucketBase[256] = acc;
        rs[n] = e;
    }
}

// packed entry: (src << 9) | (dst & 511); src < 2^17, N = 100000 fits.
__global__ void bucket_scatter_kernel(const int* __restrict__ src, const int* __restrict__ dst, int e,
                                      const int* __restrict__ bucketBase, const int* __restrict__ blockBase,
                                      unsigned* __restrict__ grouped) {
    __shared__ int cur[256];
    int t = threadIdx.x;
    cur[t] = bucketBase[t] + blockBase[blockIdx.x * 256 + t];
    __syncthreads();
    int base = blockIdx.x * CHUNK;
    #pragma unroll
    for (int k = 0; k < CHUNK / 256; k++) {
        int i = base + k * 256 + t;
        if (i < e) {
            int d = dst[i];
            int pos = atomicAdd(&cur[d >> BKT_SHIFT], 1);
            grouped[pos] = ((unsigned)src[i] << 9) | (unsigned)(d & 511);
        }
    }
}

__global__ void bucket_csr_kernel(const unsigned* __restrict__ grouped, const int* __restrict__ bucketBase,
                                  int* __restrict__ rs, int* __restrict__ csr, int n) {
    __shared__ int sdeg[BKT_NODES];
    __shared__ int sexcl[BKT_NODES];
    __shared__ int wsum[4];
    int b = blockIdx.x;
    int t = threadIdx.x;
    int nodeBase = b << BKT_SHIFT;
    int ebase = bucketBase[b], eend = bucketBase[b + 1];
    sdeg[t] = 0; sdeg[t + 256] = 0;
    __syncthreads();
    for (int e = ebase + t; e < eend; e += 256)
        atomicAdd(&sdeg[grouped[e] & 511u], 1);
    __syncthreads();
    int lane = t & 63, wid = t >> 6;
    int v0 = sdeg[2 * t], v1 = sdeg[2 * t + 1];
    int p = v0 + v1;
    int x = p;
    #pragma unroll
    for (int off = 1; off < 64; off <<= 1) {
        int y = __shfl_up(x, off, 64);
        if (lane >= off) x += y;
    }
    if (lane == 63) wsum[wid] = x;
    __syncthreads();
    if (t == 0) {
        int acc = 0;
        #pragma unroll
        for (int w = 0; w < 4; w++) { int tmp = wsum[w]; wsum[w] = acc; acc += tmp; }
    }
    __syncthreads();
    int basep = wsum[wid] + x - p;
    sexcl[2 * t] = basep;
    sexcl[2 * t + 1] = basep + v0;
    int nodes = min(BKT_NODES, n - nodeBase);
    for (int i = t; i < nodes; i += 256) rs[nodeBase + i] = ebase + sexcl[i];
    sdeg[t] = 0; sdeg[t + 256] = 0;
    __syncthreads();
    for (int e = ebase + t; e < eend; e += 256) {
        unsigned pr = grouped[e];
        int l = (int)(pr & 511u);
        int r = atomicAdd(&sdeg[l], 1);
        csr[ebase + sexcl[l] + r] = (int)(pr >> 9);
    }
}

// ---------------- Weight prep: Btg[layer][col][k] bf16; Wr half pre-scaled by 1/64 ----------------

__global__ void prep_w_kernel(const float* __restrict__ Wl, const float* __restrict__ Wr,
                              ushort* __restrict__ Btg) {
    int idx = blockIdx.x * 256 + threadIdx.x;   // 2*128*256 = 65536
    if (idx >= 65536) return;
    int l = idx >> 15;
    int col = (idx >> 8) & 127;
    int k = idx & 255;
    float v = (k < 128) ? Wl[l * H * H + k * H + col]
                        : Wr[l * H * H + (k - 128) * H + col] * FP8_INV;
    Btg[idx] = f2b(v);
}

// ---------------- Layer 0 fused: agg0 (scalar gather) + expand -> fp8 rows ----------------

__global__ void layer0_kernel(const float* __restrict__ x, const int* __restrict__ rs,
                              const int* __restrict__ csr,
                              const float* __restrict__ Wl0, const float* __restrict__ bl0,
                              const float* __restrict__ Wr0,
                              unsigned char* __restrict__ h8, int n) {
    __shared__ float sagg[256], sx[256];
    int base = blockIdx.x * 256;
    int t = threadIdx.x;
    int node = base + t;
    if (node < n) {
        int a = rs[node], b = rs[node + 1];
        float s = 0.f;
        int e = a;
        for (; e + 4 <= b; e += 4)
            s += x[csr[e]] + x[csr[e + 1]] + x[csr[e + 2]] + x[csr[e + 3]];
        for (; e < b; e++) s += x[csr[e]];
        sagg[t] = s / (float)max(b - a, 1);
        sx[t] = x[node];
    }
    __syncthreads();
    int nodes = min(256, n - base);
    #pragma unroll
    for (int pass = 0; pass < 4; pass++) {
        int nl = pass * 64 + (t >> 2);
        int p = t & 3;
        if (nl < nodes) {
            float gi = sagg[nl], xi = sx[nl];
            float v[32];
            #pragma unroll
            for (int k = 0; k < 32; k++) {
                int f = p * 32 + k;
                v[k] = fmaxf(gi * Wl0[f] + bl0[f] + xi * Wr0[f], 0.f) * FP8_SCALE;
            }
            unsigned up[8];
            #pragma unroll
            for (int d = 0; d < 8; d++) {
                int pk = __builtin_amdgcn_cvt_pk_fp8_f32(v[4 * d], v[4 * d + 1], 0, false);
                pk = __builtin_amdgcn_cvt_pk_fp8_f32(v[4 * d + 2], v[4 * d + 3], pk, true);
                up[d] = (unsigned)pk;
            }
            unsigned char* dst8 = h8 + (size_t)(base + nl) * 128 + p * 32;
            *(uint4*)dst8 = (uint4){up[0], up[1], up[2], up[3]};
            *(uint4*)(dst8 + 16) = (uint4){up[4], up[5], up[6], up[7]};
        }
    }
}

// ---------------- Aggregate from fp8 rows (round-8 shape): 2 nodes/wave, 4 slots x 8 x 16B ----------------

__global__ void aggregate8_kernel(const unsigned char* __restrict__ h8, const int* __restrict__ rs,
                                  const int* __restrict__ csr, ushort* __restrict__ aggb, int n) {
    int tid = threadIdx.x;
    int w = (tid >> 5) & 1;
    int node = blockIdx.x * 8 + (tid >> 6) * 2 + w;
    if (node >= n) return;
    int sl = (tid >> 3) & 3;
    int fl = tid & 7;
    int a = rs[node], b = rs[node + 1];
    f32x2 s[8];
    #pragma unroll
    for (int j = 0; j < 8; j++) s[j] = (f32x2){0.f, 0.f};

    int e = a;
    for (; e + 8 <= b; e += 8) {
        int n0 = csr[e + sl], n1 = csr[e + 4 + sl];
        uint4 u0 = *(const uint4*)(h8 + (size_t)n0 * 128 + 16 * fl);
        uint4 u1 = *(const uint4*)(h8 + (size_t)n1 * 128 + 16 * fl);
        unsigned dw[8] = {u0.x, u0.y, u0.z, u0.w, u1.x, u1.y, u1.z, u1.w};
        #pragma unroll
        for (int d = 0; d < 8; d++) {
            s[(d & 3) * 2]     += __builtin_amdgcn_cvt_pk_f32_fp8(dw[d], false);
            s[(d & 3) * 2 + 1] += __builtin_amdgcn_cvt_pk_f32_fp8(dw[d], true);
        }
    }
    for (; e + 4 <= b; e += 4) {
        int n0 = csr[e + sl];
        uint4 u0 = *(const uint4*)(h8 + (size_t)n0 * 128 + 16 * fl);
        unsigned dw[4] = {u0.x, u0.y, u0.z, u0.w};
        #pragma unroll
        for (int d = 0; d < 4; d++) {
            s[d * 2]     += __builtin_amdgcn_cvt_pk_f32_fp8(dw[d], false);
            s[d * 2 + 1] += __builtin_amdgcn_cvt_pk_f32_fp8(dw[d], true);
        }
    }
    if (e < b && sl < (b - e)) {
        int n0 = csr[e + sl];
        uint4 u0 = *(const uint4*)(h8 + (size_t)n0 * 128 + 16 * fl);
        unsigned dw[4] = {u0.x, u0.y, u0.z, u0.w};
        #pragma unroll
        for (int d = 0; d < 4; d++) {
            s[d * 2]     += __builtin_amdgcn_cvt_pk_f32_fp8(dw[d], false);
            s[d * 2 + 1] += __builtin_amdgcn_cvt_pk_f32_fp8(dw[d], true);
        }
    }
    #pragma unroll
    for (int j = 0; j < 8; j++) {
        s[j].x += __shfl_xor(s[j].x, 8, 64);
        s[j].y += __shfl_xor(s[j].y, 8, 64);
        s[j].x += __shfl_xor(s[j].x, 16, 64);
        s[j].y += __shfl_xor(s[j].y, 16, 64);
    }
    if (sl == 0) {
        float inv = FP8_INV / (float)max(b - a, 1);
        short8 o0, o1;
        #pragma unroll
        for (int j = 0; j < 4; j++) {
            o0[2 * j]     = (short)f2b(s[j].x * inv);
            o0[2 * j + 1] = (short)f2b(s[j].y * inv);
            o1[2 * j]     = (short)f2b(s[j + 4].x * inv);
            o1[2 * j + 1] = (short)f2b(s[j + 4].y * inv);
        }
        ushort* dstp = aggb + (size_t)node * H + 16 * fl;
        *(short8*)dstp = o0;
        *(short8*)(dstp + 8) = o1;
    }
}

// ---------------- Fused dual GEMM: A = [aggb bf16 | h8 fp8->bf16 in-reg], B in registers ----------------
// Root-half weights pre-scaled by 1/64 (fp8 scale). POOL=false: write fp8 rows only.

template<bool POOL>
__global__ __launch_bounds__(256, 2) void gemm_kernel(
    const ushort* __restrict__ aggb, const unsigned char* __restrict__ h8,
    const ushort* __restrict__ Btg,   // [128][256] bf16 for this layer
    const float* __restrict__ bias,
    unsigned char* __restrict__ out8,
    float* __restrict__ partial, int nblk, int n) {
    __shared__ float sums[2][128];
    int tid = threadIdx.x;
    int wave = tid >> 6, lane = tid & 63;
    int l15 = lane & 15, lhi = lane >> 4;
    int colhalf = wave & 1;
    int rowsub = wave >> 1;
    int colbase = colhalf * 64;

    short8 bf[4][8];
    #pragma unroll
    for (int c2 = 0; c2 < 4; c2++) {
        const ushort* wp = Btg + (colbase + c2 * 16 + l15) * 256 + lhi * 8;
        #pragma unroll
        for (int s = 0; s < 8; s++)
            bf[c2][s] = *(const short8*)(wp + s * 32);
    }
    f32x4 bias_v[4];
    #pragma unroll
    for (int c2 = 0; c2 < 4; c2++)
        bias_v[c2] = *(const f32x4*)(bias + colbase + c2 * 16 + lhi * 4);

    f32x4 fs[4];
    #pragma unroll
    for (int c2 = 0; c2 < 4; c2++) fs[c2] = (f32x4){0.f, 0.f, 0.f, 0.f};

    for (int r0 = blockIdx.x * 32; r0 < n; r0 += nblk * 32) {
        int row = r0 + rowsub * 16 + l15;
        int arow = min(row, n - 1);
        short8 af[8];
        #pragma unroll
        for (int s = 0; s < 4; s++)
            af[s] = *(const short8*)(aggb + (size_t)arow * H + s * 32 + lhi * 8);
        #pragma unroll
        for (int s = 0; s < 4; s++) {
            uint2 u = *(const uint2*)(h8 + (size_t)arow * 128 + s * 32 + lhi * 8);
            f32x2 a0 = __builtin_amdgcn_cvt_pk_f32_fp8(u.x, false);
            f32x2 a1 = __builtin_amdgcn_cvt_pk_f32_fp8(u.x, true);
            f32x2 a2 = __builtin_amdgcn_cvt_pk_f32_fp8(u.y, false);
            f32x2 a3 = __builtin_amdgcn_cvt_pk_f32_fp8(u.y, true);
            // truncate-pack pairs of f32 to bf16x2 (scale folded into weights)
            unsigned d0 = __builtin_amdgcn_perm(__builtin_bit_cast(unsigned, a0.y), __builtin_bit_cast(unsigned, a0.x), 0x07060302u);
            unsigned d1 = __builtin_amdgcn_perm(__builtin_bit_cast(unsigned, a1.y), __builtin_bit_cast(unsigned, a1.x), 0x07060302u);
            unsigned d2 = __builtin_amdgcn_perm(__builtin_bit_cast(unsigned, a2.y), __builtin_bit_cast(unsigned, a2.x), 0x07060302u);
            unsigned d3 = __builtin_amdgcn_perm(__builtin_bit_cast(unsigned, a3.y), __builtin_bit_cast(unsigned, a3.x), 0x07060302u);
            union { unsigned u4[4]; short8 s8; } pk;
            pk.u4[0] = d0; pk.u4[1] = d1; pk.u4[2] = d2; pk.u4[3] = d3;
            af[4 + s] = pk.s8;
        }
        f32x4 acc[4];
        #pragma unroll
        for (int c2 = 0; c2 < 4; c2++) acc[c2] = (f32x4){0.f, 0.f, 0.f, 0.f};
        #pragma unroll
        for (int s = 0; s < 8; s++) {
            #pragma unroll
            for (int c2 = 0; c2 < 4; c2++)
                acc[c2] = __builtin_amdgcn_mfma_f32_16x16x32_bf16(bf[c2][s], af[s], acc[c2], 0, 0, 0);
        }
        if (row < n) {
            if (POOL) {
                #pragma unroll
                for (int c2 = 0; c2 < 4; c2++)
                    #pragma unroll
                    for (int r = 0; r < 4; r++)
                        fs[c2][r] += fmaxf(acc[c2][r] + bias_v[c2][r], 0.f);
            } else {
                #pragma unroll
                for (int c2 = 0; c2 < 4; c2++) {
                    float v0 = fmaxf(acc[c2][0] + bias_v[c2][0], 0.f) * FP8_SCALE;
                    float v1 = fmaxf(acc[c2][1] + bias_v[c2][1], 0.f) * FP8_SCALE;
                    float v2 = fmaxf(acc[c2][2] + bias_v[c2][2], 0.f) * FP8_SCALE;
                    float v3 = fmaxf(acc[c2][3] + bias_v[c2][3], 0.f) * FP8_SCALE;
                    int pk = __builtin_amdgcn_cvt_pk_fp8_f32(v0, v1, 0, false);
                    pk = __builtin_amdgcn_cvt_pk_fp8_f32(v2, v3, pk, true);
                    *(unsigned*)(out8 + (size_t)row * 128 + colbase + c2 * 16 + lhi * 4) = (unsigned)pk;
                }
            }
        }
    }

    if (POOL) {
        #pragma unroll
        for (int c2 = 0; c2 < 4; c2++) {
            #pragma unroll
            for (int m = 1; m < 16; m <<= 1) {
                #pragma unroll
                for (int r = 0; r < 4; r++)
                    fs[c2][r] += __shfl_xor(fs[c2][r], m, 64);
            }
        }
        if (l15 == 0) {
            #pragma unroll
            for (int c2 = 0; c2 < 4; c2++)
                #pragma unroll
                for (int r = 0; r < 4; r++)
                    sums[rowsub][colbase + c2 * 16 + lhi * 4 + r] = fs[c2][r];
        }
        __syncthreads();
        if (tid < 128)
            partial[(size_t)blockIdx.x * 128 + tid] = sums[0][tid] + sums[1][tid];
    }
}

// ---------------- Fused pooling reduce + MLP (single block, 256 threads) ----------------

__global__ void pool_mlp_kernel(const float* __restrict__ partial, int nblk, float invn,
                                const float* __restrict__ Wv, const float* __restrict__ bv,
                                const float* __restrict__ temp, const float* __restrict__ tt,
                                const float* __restrict__ Wm1, const float* __restrict__ bm1,
                                const float* __restrict__ Wm2, const float* __restrict__ bm2,
                                float* __restrict__ out) {
    __shared__ float ps[256];
    __shared__ float pooled[128];
    __shared__ float feat[66];
    __shared__ float red[4];
    int t = threadIdx.x;  // 256
    int f = t & 127, hh = t >> 7;
    float s = 0.f;
    int half = nblk >> 1;
    for (int b = hh * half; b < (hh + 1) * half; b++) s += partial[(size_t)b * 128 + f];
    ps[t] = s;
    __syncthreads();
    if (t < 128) pooled[t] = (ps[t] + ps[t + 128]) * invn;
    __syncthreads();
    if (t < 64) {
        float z = bv[t];
        for (int k = 0; k < H; k++) z += pooled[k] * Wv[k * 64 + t];
        feat[t] = z;
    }
    if (t == 64) feat[64] = temp[0];
    if (t == 65) feat[65] = tt[0];
    __syncthreads();
    float p = 0.f;
    if (t < 128) {
        float m = bm1[t];
        for (int k = 0; k < 66; k++) m += feat[k] * Wm1[k * H + t];
        m = fmaxf(m, 0.f);
        p = m * Wm2[t];
    }
    #pragma unroll
    for (int off = 32; off > 0; off >>= 1) p += __shfl_down(p, off, 64);
    if ((t & 63) == 0) red[t >> 6] = p;
    __syncthreads();
    if (t == 0) {
        float x = red[0] + red[1] + red[2] + red[3] + bm2[0];
        out[0] = (x > 20.f) ? x : log1pf(expf(x));
    }
}

// ---------------- Launch ----------------

extern "C" void kernel_launch(void* const* d_in, const int* in_sizes, int n_in,
                              void* d_out, int out_size, void* d_ws, size_t ws_size,
                              hipStream_t stream) {
    const float* node_feats = (const float*)d_in[0];
    const int* edge_index = (const int*)d_in[1];
    const float* temp = (const float*)d_in[3];
    const float* tt   = (const float*)d_in[4];
    const float* Wl0 = (const float*)d_in[5];
    const float* bl0 = (const float*)d_in[6];
    const float* Wr0 = (const float*)d_in[7];
    const float* Wl  = (const float*)d_in[8];
    const float* bl  = (const float*)d_in[9];
    const float* Wr  = (const float*)d_in[10];
    const float* Wv  = (const float*)d_in[11];
    const float* bv  = (const float*)d_in[12];
    const float* Wm1 = (const float*)d_in[13];
    const float* bm1 = (const float*)d_in[14];
    const float* Wm2 = (const float*)d_in[15];
    const float* bm2 = (const float*)d_in[16];

    const int N = in_sizes[0];
    const int E = in_sizes[1] / 2;
    const int* src = edge_index;
    const int* dst = edge_index + E;

    size_t NH = (size_t)N * H;
    ushort* aggb = (ushort*)d_ws;                     // N*H bf16
    ushort* Btg  = aggb + NH;                         // 2*128*256 bf16
    unsigned char* hA8 = (unsigned char*)(Btg + 65536);  // N*128 fp8
    unsigned char* hB8 = hA8 + NH;                    // N*128 fp8
    unsigned* grouped = (unsigned*)(hB8 + NH);        // E packed
    int* csr     = (int*)(grouped + E);               // E
    int* rs      = csr + E;                           // N+1
    int* bucketCount = rs + (N + 1);                  // 256
    int* bucketBase  = bucketCount + 256;             // 257
    int* blockBase   = bucketBase + 257;              // NBLK*256
    int NBLK = (E + CHUNK - 1) / CHUNK;
    float* partial = (float*)(blockBase + NBLK * 256);  // GEMM_GRID*128

    int NB = (N + BKT_NODES - 1) / BKT_NODES;

    // CSR build (bucketed, packed)
    hipMemsetAsync(bucketCount, 0, 256 * sizeof(int), stream);
    bucket_hist_kernel<<<NBLK, 256, 0, stream>>>(dst, E, bucketCount, blockBase);
    bucket_scan_kernel<<<1, 64, 0, stream>>>(bucketCount, bucketBase, rs, N, E);
    bucket_scatter_kernel<<<NBLK, 256, 0, stream>>>(src, dst, E, bucketBase, blockBase, grouped);
    bucket_csr_kernel<<<NB, 256, 0, stream>>>(grouped, bucketBase, rs, csr, N);

    // Weights -> bf16 transposed [layer][col][k], Wr half pre-scaled by 1/64
    prep_w_kernel<<<256, 256, 0, stream>>>(Wl, Wr, Btg);

    // Layer 0 fused: agg0 + expand -> hA8 (fp8 rows only)
    layer0_kernel<<<(N + 255) / 256, 256, 0, stream>>>(node_feats, rs, csr, Wl0, bl0, Wr0, hA8, N);

    // Layer 1: fp8 gather-mean -> aggb; gemm -> hB8
    aggregate8_kernel<<<(N + 7) / 8, 256, 0, stream>>>(hA8, rs, csr, aggb, N);
    gemm_kernel<false><<<GEMM_GRID, 256, 0, stream>>>(aggb, hA8, Btg, bl, hB8, nullptr, GEMM_GRID, N);

    // Layer 2: fp8 gather-mean -> aggb; gemm (fused pooling)
    aggregate8_kernel<<<(N + 7) / 8, 256, 0, stream>>>(hB8, rs, csr, aggb, N);
    gemm_kernel<true><<<GEMM_GRID, 256, 0, stream>>>(aggb, hB8, Btg + 32768, bl + H, nullptr, partial, GEMM_GRID, N);

    // Fused pooling reduce + MLP
    pool_mlp_kernel<<<1, 256, 0, stream>>>(partial, GEMM_GRID, 1.0f / (float)N,
                                           Wv, bv, temp, tt, Wm1, bm1, Wm2, bm2, (float*)d_out);
}

// Round 12
// 235.864 us; speedup vs baseline: 1.7442x; 1.2438x over previous
//
#include <hip/hip_runtime.h>
#include <hip/hip_bf16.h>
#include <math.h>

#define H 128
#define BKT_SHIFT 9
#define BKT_NODES 512
#define CHUNK 2048   // edges per block in phase A/B
#define GEMM_GRID 512
#define FP8_SCALE 64.0f
#define FP8_INV (1.0f / 64.0f)

typedef __attribute__((ext_vector_type(8))) short short8;
typedef __attribute__((ext_vector_type(4))) float f32x4;
typedef __attribute__((ext_vector_type(2))) float f32x2;

static __device__ __forceinline__ ushort f2b(float v) {
    union { float f; unsigned u; } x; x.f = v;
    unsigned r = x.u + 0x7fffu + ((x.u >> 16) & 1u);
    return (ushort)(r >> 16);
}

// ---------------- Bucketed CSR build ----------------

__global__ void bucket_hist_kernel(const int* __restrict__ dst, int e,
                                   int* __restrict__ bucketCount, int* __restrict__ blockBase) {
    __shared__ int hist[256];
    int t = threadIdx.x;
    hist[t] = 0;
    __syncthreads();
    int base = blockIdx.x * CHUNK;
    #pragma unroll
    for (int k = 0; k < CHUNK / 256; k++) {
        int i = base + k * 256 + t;
        if (i < e) atomicAdd(&hist[dst[i] >> BKT_SHIFT], 1);
    }
    __syncthreads();
    blockBase[blockIdx.x * 256 + t] = atomicAdd(&bucketCount[t], hist[t]);
}

__global__ void bucket_scan_kernel(const int* __restrict__ bucketCount, int* __restrict__ bucketBase,
                                   int* __restrict__ rs, int n, int e) {
    if (threadIdx.x == 0 && blockIdx.x == 0) {
        int acc = 0;
        for (int i = 0; i < 256; i++) { bucketBase[i] = acc; acc += bucketCount[i]; }
        bucketBase[256] = acc;
        rs[n] = e;
    }
}

// packed entry: (src << 9) | (dst & 511); src < 2^17, N = 100000 fits.
__global__ void bucket_scatter_kernel(const int* __restrict__ src, const int* __restrict__ dst, int e,
                                      const int* __restrict__ bucketBase, const int* __restrict__ blockBase,
                                      unsigned* __restrict__ grouped) {
    __shared__ int cur[256];
    int t = threadIdx.x;
    cur[t] = bucketBase[t] + blockBase[blockIdx.x * 256 + t];
    __syncthreads();
    int base = blockIdx.x * CHUNK;
    #pragma unroll
    for (int k = 0; k < CHUNK / 256; k++) {
        int i = base + k * 256 + t;
        if (i < e) {
            int d = dst[i];
            int pos = atomicAdd(&cur[d >> BKT_SHIFT], 1);
            grouped[pos] = ((unsigned)src[i] << 9) | (unsigned)(d & 511);
        }
    }
}

__global__ void bucket_csr_kernel(const unsigned* __restrict__ grouped, const int* __restrict__ bucketBase,
                                  int* __restrict__ rs, int* __restrict__ csr, int n) {
    __shared__ int sdeg[BKT_NODES];
    __shared__ int sexcl[BKT_NODES];
    __shared__ int wsum[4];
    int b = blockIdx.x;
    int t = threadIdx.x;
    int nodeBase = b << BKT_SHIFT;
    int ebase = bucketBase[b], eend = bucketBase[b + 1];
    sdeg[t] = 0; sdeg[t + 256] = 0;
    __syncthreads();
    for (int e = ebase + t; e < eend; e += 256)
        atomicAdd(&sdeg[grouped[e] & 511u], 1);
    __syncthreads();
    int lane = t & 63, wid = t >> 6;
    int v0 = sdeg[2 * t], v1 = sdeg[2 * t + 1];
    int p = v0 + v1;
    int x = p;
    #pragma unroll
    for (int off = 1; off < 64; off <<= 1) {
        int y = __shfl_up(x, off, 64);
        if (lane >= off) x += y;
    }
    if (lane == 63) wsum[wid] = x;
    __syncthreads();
    if (t == 0) {
        int acc = 0;
        #pragma unroll
        for (int w = 0; w < 4; w++) { int tmp = wsum[w]; wsum[w] = acc; acc += tmp; }
    }
    __syncthreads();
    int basep = wsum[wid] + x - p;
    sexcl[2 * t] = basep;
    sexcl[2 * t + 1] = basep + v0;
    int nodes = min(BKT_NODES, n - nodeBase);
    for (int i = t; i < nodes; i += 256) rs[nodeBase + i] = ebase + sexcl[i];
    sdeg[t] = 0; sdeg[t + 256] = 0;
    __syncthreads();
    for (int e = ebase + t; e < eend; e += 256) {
        unsigned pr = grouped[e];
        int l = (int)(pr & 511u);
        int r = atomicAdd(&sdeg[l], 1);
        csr[ebase + sexcl[l] + r] = (int)(pr >> 9);
    }
}

// ---------------- Weight prep: Btg[layer][col][k] bf16; Wr half pre-scaled by 1/64 ----------------

__global__ void prep_w_kernel(const float* __restrict__ Wl, const float* __restrict__ Wr,
                              ushort* __restrict__ Btg) {
    int idx = blockIdx.x * 256 + threadIdx.x;   // 2*128*256 = 65536
    if (idx >= 65536) return;
    int l = idx >> 15;
    int col = (idx >> 8) & 127;
    int k = idx & 255;
    float v = (k < 128) ? Wl[l * H * H + k * H + col]
                        : Wr[l * H * H + (k - 128) * H + col] * FP8_INV;
    Btg[idx] = f2b(v);
}

// ---------------- Layer 0 fused: agg0 (scalar gather) + expand -> fp8 rows ----------------

__global__ void layer0_kernel(const float* __restrict__ x, const int* __restrict__ rs,
                              const int* __restrict__ csr,
                              const float* __restrict__ Wl0, const float* __restrict__ bl0,
                              const float* __restrict__ Wr0,
                              unsigned char* __restrict__ h8, int n) {
    __shared__ float sagg[256], sx[256];
    int base = blockIdx.x * 256;
    int t = threadIdx.x;
    int node = base + t;
    if (node < n) {
        int a = rs[node], b = rs[node + 1];
        float s = 0.f;
        int e = a;
        for (; e + 4 <= b; e += 4)
            s += x[csr[e]] + x[csr[e + 1]] + x[csr[e + 2]] + x[csr[e + 3]];
        for (; e < b; e++) s += x[csr[e]];
        sagg[t] = s / (float)max(b - a, 1);
        sx[t] = x[node];
    }
    __syncthreads();
    int nodes = min(256, n - base);
    #pragma unroll
    for (int pass = 0; pass < 4; pass++) {
        int nl = pass * 64 + (t >> 2);
        int p = t & 3;
        if (nl < nodes) {
            float gi = sagg[nl], xi = sx[nl];
            float v[32];
            #pragma unroll
            for (int k = 0; k < 32; k++) {
                int f = p * 32 + k;
                v[k] = fmaxf(gi * Wl0[f] + bl0[f] + xi * Wr0[f], 0.f) * FP8_SCALE;
            }
            unsigned up[8];
            #pragma unroll
            for (int d = 0; d < 8; d++) {
                int pk = __builtin_amdgcn_cvt_pk_fp8_f32(v[4 * d], v[4 * d + 1], 0, false);
                pk = __builtin_amdgcn_cvt_pk_fp8_f32(v[4 * d + 2], v[4 * d + 3], pk, true);
                up[d] = (unsigned)pk;
            }
            unsigned char* dst8 = h8 + (size_t)(base + nl) * 128 + p * 32;
            *(uint4*)dst8 = (uint4){up[0], up[1], up[2], up[3]};
            *(uint4*)(dst8 + 16) = (uint4){up[4], up[5], up[6], up[7]};
        }
    }
}

// ---------------- Aggregate from fp8 rows: 2 nodes/wave, 4 slots x 8 x 16B ----------------

__global__ void aggregate8_kernel(const unsigned char* __restrict__ h8, const int* __restrict__ rs,
                                  const int* __restrict__ csr, ushort* __restrict__ aggb, int n) {
    int tid = threadIdx.x;
    int w = (tid >> 5) & 1;
    int node = blockIdx.x * 8 + (tid >> 6) * 2 + w;
    if (node >= n) return;
    int sl = (tid >> 3) & 3;
    int fl = tid & 7;
    int a = rs[node], b = rs[node + 1];
    f32x2 s[8];
    #pragma unroll
    for (int j = 0; j < 8; j++) s[j] = (f32x2){0.f, 0.f};

    int e = a;
    for (; e + 8 <= b; e += 8) {
        int n0 = csr[e + sl], n1 = csr[e + 4 + sl];
        uint4 u0 = *(const uint4*)(h8 + (size_t)n0 * 128 + 16 * fl);
        uint4 u1 = *(const uint4*)(h8 + (size_t)n1 * 128 + 16 * fl);
        unsigned dw[8] = {u0.x, u0.y, u0.z, u0.w, u1.x, u1.y, u1.z, u1.w};
        #pragma unroll
        for (int d = 0; d < 8; d++) {
            s[(d & 3) * 2]     += __builtin_amdgcn_cvt_pk_f32_fp8(dw[d], false);
            s[(d & 3) * 2 + 1] += __builtin_amdgcn_cvt_pk_f32_fp8(dw[d], true);
        }
    }
    for (; e + 4 <= b; e += 4) {
        int n0 = csr[e + sl];
        uint4 u0 = *(const uint4*)(h8 + (size_t)n0 * 128 + 16 * fl);
        unsigned dw[4] = {u0.x, u0.y, u0.z, u0.w};
        #pragma unroll
        for (int d = 0; d < 4; d++) {
            s[d * 2]     += __builtin_amdgcn_cvt_pk_f32_fp8(dw[d], false);
            s[d * 2 + 1] += __builtin_amdgcn_cvt_pk_f32_fp8(dw[d], true);
        }
    }
    if (e < b && sl < (b - e)) {
        int n0 = csr[e + sl];
        uint4 u0 = *(const uint4*)(h8 + (size_t)n0 * 128 + 16 * fl);
        unsigned dw[4] = {u0.x, u0.y, u0.z, u0.w};
        #pragma unroll
        for (int d = 0; d < 4; d++) {
            s[d * 2]     += __builtin_amdgcn_cvt_pk_f32_fp8(dw[d], false);
            s[d * 2 + 1] += __builtin_amdgcn_cvt_pk_f32_fp8(dw[d], true);
        }
    }
    #pragma unroll
    for (int j = 0; j < 8; j++) {
        s[j].x += __shfl_xor(s[j].x, 8, 64);
        s[j].y += __shfl_xor(s[j].y, 8, 64);
        s[j].x += __shfl_xor(s[j].x, 16, 64);
        s[j].y += __shfl_xor(s[j].y, 16, 64);
    }
    if (sl == 0) {
        float inv = FP8_INV / (float)max(b - a, 1);
        short8 o0, o1;
        #pragma unroll
        for (int j = 0; j < 4; j++) {
            o0[2 * j]     = (short)f2b(s[j].x * inv);
            o0[2 * j + 1] = (short)f2b(s[j].y * inv);
            o1[2 * j]     = (short)f2b(s[j + 4].x * inv);
            o1[2 * j + 1] = (short)f2b(s[j + 4].y * inv);
        }
        ushort* dstp = aggb + (size_t)node * H + 16 * fl;
        *(short8*)dstp = o0;
        *(short8*)(dstp + 8) = o1;
    }
}

// ---------------- Fused dual GEMM: A = [aggb bf16 | h8 fp8->bf16 in-reg], B in registers ----------------

template<bool POOL>
__global__ __launch_bounds__(256, 2) void gemm_kernel(
    const ushort* __restrict__ aggb, const unsigned char* __restrict__ h8,
    const ushort* __restrict__ Btg,   // [128][256] bf16 for this layer
    const float* __restrict__ bias,
    unsigned char* __restrict__ out8,
    float* __restrict__ partial, int nblk, int n) {
    __shared__ float sums[2][128];
    int tid = threadIdx.x;
    int wave = tid >> 6, lane = tid & 63;
    int l15 = lane & 15, lhi = lane >> 4;
    int colhalf = wave & 1;
    int rowsub = wave >> 1;
    int colbase = colhalf * 64;

    short8 bf[4][8];
    #pragma unroll
    for (int c2 = 0; c2 < 4; c2++) {
        const ushort* wp = Btg + (colbase + c2 * 16 + l15) * 256 + lhi * 8;
        #pragma unroll
        for (int s = 0; s < 8; s++)
            bf[c2][s] = *(const short8*)(wp + s * 32);
    }
    f32x4 bias_v[4];
    #pragma unroll
    for (int c2 = 0; c2 < 4; c2++)
        bias_v[c2] = *(const f32x4*)(bias + colbase + c2 * 16 + lhi * 4);

    f32x4 fs[4];
    #pragma unroll
    for (int c2 = 0; c2 < 4; c2++) fs[c2] = (f32x4){0.f, 0.f, 0.f, 0.f};

    for (int r0 = blockIdx.x * 32; r0 < n; r0 += nblk * 32) {
        int row = r0 + rowsub * 16 + l15;
        int arow = min(row, n - 1);
        short8 af[8];
        #pragma unroll
        for (int s = 0; s < 4; s++)
            af[s] = *(const short8*)(aggb + (size_t)arow * H + s * 32 + lhi * 8);
        #pragma unroll
        for (int s = 0; s < 4; s++) {
            uint2 u = *(const uint2*)(h8 + (size_t)arow * 128 + s * 32 + lhi * 8);
            f32x2 a0 = __builtin_amdgcn_cvt_pk_f32_fp8(u.x, false);
            f32x2 a1 = __builtin_amdgcn_cvt_pk_f32_fp8(u.x, true);
            f32x2 a2 = __builtin_amdgcn_cvt_pk_f32_fp8(u.y, false);
            f32x2 a3 = __builtin_amdgcn_cvt_pk_f32_fp8(u.y, true);
            unsigned d0 = __builtin_amdgcn_perm(__builtin_bit_cast(unsigned, a0.y), __builtin_bit_cast(unsigned, a0.x), 0x07060302u);
            unsigned d1 = __builtin_amdgcn_perm(__builtin_bit_cast(unsigned, a1.y), __builtin_bit_cast(unsigned, a1.x), 0x07060302u);
            unsigned d2 = __builtin_amdgcn_perm(__builtin_bit_cast(unsigned, a2.y), __builtin_bit_cast(unsigned, a2.x), 0x07060302u);
            unsigned d3 = __builtin_amdgcn_perm(__builtin_bit_cast(unsigned, a3.y), __builtin_bit_cast(unsigned, a3.x), 0x07060302u);
            union { unsigned u4[4]; short8 s8; } pk;
            pk.u4[0] = d0; pk.u4[1] = d1; pk.u4[2] = d2; pk.u4[3] = d3;
            af[4 + s] = pk.s8;
        }
        f32x4 acc[4];
        #pragma unroll
        for (int c2 = 0; c2 < 4; c2++) acc[c2] = (f32x4){0.f, 0.f, 0.f, 0.f};
        #pragma unroll
        for (int s = 0; s < 8; s++) {
            #pragma unroll
            for (int c2 = 0; c2 < 4; c2++)
                acc[c2] = __builtin_amdgcn_mfma_f32_16x16x32_bf16(bf[c2][s], af[s], acc[c2], 0, 0, 0);
        }
        if (row < n) {
            if (POOL) {
                #pragma unroll
                for (int c2 = 0; c2 < 4; c2++)
                    #pragma unroll
                    for (int r = 0; r < 4; r++)
                        fs[c2][r] += fmaxf(acc[c2][r] + bias_v[c2][r], 0.f);
            } else {
                #pragma unroll
                for (int c2 = 0; c2 < 4; c2++) {
                    float v0 = fmaxf(acc[c2][0] + bias_v[c2][0], 0.f) * FP8_SCALE;
                    float v1 = fmaxf(acc[c2][1] + bias_v[c2][1], 0.f) * FP8_SCALE;
                    float v2 = fmaxf(acc[c2][2] + bias_v[c2][2], 0.f) * FP8_SCALE;
                    float v3 = fmaxf(acc[c2][3] + bias_v[c2][3], 0.f) * FP8_SCALE;
                    int pk = __builtin_amdgcn_cvt_pk_fp8_f32(v0, v1, 0, false);
                    pk = __builtin_amdgcn_cvt_pk_fp8_f32(v2, v3, pk, true);
                    *(unsigned*)(out8 + (size_t)row * 128 + colbase + c2 * 16 + lhi * 4) = (unsigned)pk;
                }
            }
        }
    }

    if (POOL) {
        #pragma unroll
        for (int c2 = 0; c2 < 4; c2++) {
            #pragma unroll
            for (int m = 1; m < 16; m <<= 1) {
                #pragma unroll
                for (int r = 0; r < 4; r++)
                    fs[c2][r] += __shfl_xor(fs[c2][r], m, 64);
            }
        }
        if (l15 == 0) {
            #pragma unroll
            for (int c2 = 0; c2 < 4; c2++)
                #pragma unroll
                for (int r = 0; r < 4; r++)
                    sums[rowsub][colbase + c2 * 16 + lhi * 4 + r] = fs[c2][r];
        }
        __syncthreads();
        if (tid < 128)
            partial[(size_t)tid * nblk + blockIdx.x] = sums[0][tid] + sums[1][tid];  // transposed
    }
}

// ---------------- Final pooling reduce: one wave per feature, contiguous row ----------------

__global__ void pool_reduce_kernel(const float* __restrict__ partial, float* __restrict__ pooled,
                                   int nb, float invn) {
    int j = blockIdx.x;      // feature
    int t = threadIdx.x;     // 64 (one wave)
    float s = 0.f;
    for (int b = t; b < nb; b += 64) s += partial[(size_t)j * nb + b];
    #pragma unroll
    for (int off = 32; off > 0; off >>= 1) s += __shfl_down(s, off, 64);
    if (t == 0) pooled[j] = s * invn;
}

// ---------------- Final MLP ----------------

__global__ void mlp_kernel(const float* __restrict__ pooled,
                           const float* __restrict__ Wv, const float* __restrict__ bv,
                           const float* __restrict__ temp, const float* __restrict__ tt,
                           const float* __restrict__ Wm1, const float* __restrict__ bm1,
                           const float* __restrict__ Wm2, const float* __restrict__ bm2,
                           float* __restrict__ out) {
    __shared__ float feat[66];
    __shared__ float red[2];
    int j = threadIdx.x;  // 128 threads
    if (j < 64) {
        float s = bv[j];
        for (int k = 0; k < H; k++) s += pooled[k] * Wv[k * 64 + j];
        feat[j] = s;
    }
    if (j == 64) feat[64] = temp[0];
    if (j == 65) feat[65] = tt[0];
    __syncthreads();
    float m = bm1[j];
    for (int k = 0; k < 66; k++) m += feat[k] * Wm1[k * H + j];
    m = fmaxf(m, 0.f);
    float p = m * Wm2[j];
    #pragma unroll
    for (int off = 32; off > 0; off >>= 1) p += __shfl_down(p, off, 64);
    if ((j & 63) == 0) red[j >> 6] = p;
    __syncthreads();
    if (j == 0) {
        float x = red[0] + red[1] + bm2[0];
        out[0] = (x > 20.f) ? x : log1pf(expf(x));
    }
}

// ---------------- Launch ----------------

extern "C" void kernel_launch(void* const* d_in, const int* in_sizes, int n_in,
                              void* d_out, int out_size, void* d_ws, size_t ws_size,
                              hipStream_t stream) {
    const float* node_feats = (const float*)d_in[0];
    const int* edge_index = (const int*)d_in[1];
    const float* temp = (const float*)d_in[3];
    const float* tt   = (const float*)d_in[4];
    const float* Wl0 = (const float*)d_in[5];
    const float* bl0 = (const float*)d_in[6];
    const float* Wr0 = (const float*)d_in[7];
    const float* Wl  = (const float*)d_in[8];
    const float* bl  = (const float*)d_in[9];
    const float* Wr  = (const float*)d_in[10];
    const float* Wv  = (const float*)d_in[11];
    const float* bv  = (const float*)d_in[12];
    const float* Wm1 = (const float*)d_in[13];
    const float* bm1 = (const float*)d_in[14];
    const float* Wm2 = (const float*)d_in[15];
    const float* bm2 = (const float*)d_in[16];

    const int N = in_sizes[0];
    const int E = in_sizes[1] / 2;
    const int* src = edge_index;
    const int* dst = edge_index + E;

    size_t NH = (size_t)N * H;
    ushort* aggb = (ushort*)d_ws;                     // N*H bf16
    ushort* Btg  = aggb + NH;                         // 2*128*256 bf16
    unsigned char* hA8 = (unsigned char*)(Btg + 65536);  // N*128 fp8
    unsigned char* hB8 = hA8 + NH;                    // N*128 fp8
    unsigned* grouped = (unsigned*)(hB8 + NH);        // E packed
    int* csr     = (int*)(grouped + E);               // E
    int* rs      = csr + E;                           // N+1
    int* bucketCount = rs + (N + 1);                  // 256
    int* bucketBase  = bucketCount + 256;             // 257
    int* blockBase   = bucketBase + 257;              // NBLK*256
    int NBLK = (E + CHUNK - 1) / CHUNK;
    float* partial = (float*)(blockBase + NBLK * 256);  // 128*GEMM_GRID (transposed)
    float* pooled  = partial + (size_t)H * GEMM_GRID;   // H

    int NB = (N + BKT_NODES - 1) / BKT_NODES;

    // CSR build (bucketed, packed)
    hipMemsetAsync(bucketCount, 0, 256 * sizeof(int), stream);
    bucket_hist_kernel<<<NBLK, 256, 0, stream>>>(dst, E, bucketCount, blockBase);
    bucket_scan_kernel<<<1, 64, 0, stream>>>(bucketCount, bucketBase, rs, N, E);
    bucket_scatter_kernel<<<NBLK, 256, 0, stream>>>(src, dst, E, bucketBase, blockBase, grouped);
    bucket_csr_kernel<<<NB, 256, 0, stream>>>(grouped, bucketBase, rs, csr, N);

    // Weights -> bf16 transposed [layer][col][k], Wr half pre-scaled by 1/64
    prep_w_kernel<<<256, 256, 0, stream>>>(Wl, Wr, Btg);

    // Layer 0 fused: agg0 + expand -> hA8 (fp8 rows only)
    layer0_kernel<<<(N + 255) / 256, 256, 0, stream>>>(node_feats, rs, csr, Wl0, bl0, Wr0, hA8, N);

    // Layer 1: fp8 gather-mean -> aggb; gemm -> hB8
    aggregate8_kernel<<<(N + 7) / 8, 256, 0, stream>>>(hA8, rs, csr, aggb, N);
    gemm_kernel<false><<<GEMM_GRID, 256, 0, stream>>>(aggb, hA8, Btg, bl, hB8, nullptr, GEMM_GRID, N);

    // Layer 2: fp8 gather-mean -> aggb; gemm (fused pooling)
    aggregate8_kernel<<<(N + 7) / 8, 256, 0, stream>>>(hB8, rs, csr, aggb, N);
    gemm_kernel<true><<<GEMM_GRID, 256, 0, stream>>>(aggb, hB8, Btg + 32768, bl + H, nullptr, partial, GEMM_GRID, N);

    // Final pooling reduce + MLP
    pool_reduce_kernel<<<H, 64, 0, stream>>>(partial, pooled, GEMM_GRID, 1.0f / (float)N);
    mlp_kernel<<<1, H, 0, stream>>>(pooled, Wv, bv, temp, tt, Wm1, bm1, Wm2, bm2, (float*)d_out);
}

// Round 16
// 234.318 us; speedup vs baseline: 1.7557x; 1.0066x over previous
//
#include <hip/hip_runtime.h>
#include <hip/hip_bf16.h>
#include <math.h>

#define H 128
#define BKT_SHIFT 9
#define BKT_NODES 512
#define CHUNK 2048   // edges per block in phase A/B
#define GEMM_GRID 512
#define FP8_SCALE 64.0f
#define FP8_INV (1.0f / 64.0f)

typedef __attribute__((ext_vector_type(8))) short short8;
typedef __attribute__((ext_vector_type(4))) float f32x4;
typedef __attribute__((ext_vector_type(2))) float f32x2;

static __device__ __forceinline__ ushort f2b(float v) {
    union { float f; unsigned u; } x; x.f = v;
    unsigned r = x.u + 0x7fffu + ((x.u >> 16) & 1u);
    return (ushort)(r >> 16);
}

// ---------------- Bucketed CSR build ----------------

__global__ void bucket_hist_kernel(const int* __restrict__ dst, int e,
                                   int* __restrict__ bucketCount, int* __restrict__ blockBase) {
    __shared__ int hist[256];
    int t = threadIdx.x;
    hist[t] = 0;
    __syncthreads();
    int base = blockIdx.x * CHUNK;
    #pragma unroll
    for (int k = 0; k < CHUNK / 256; k++) {
        int i = base + k * 256 + t;
        if (i < e) atomicAdd(&hist[dst[i] >> BKT_SHIFT], 1);
    }
    __syncthreads();
    blockBase[blockIdx.x * 256 + t] = atomicAdd(&bucketCount[t], hist[t]);
}

__global__ void bucket_scan_kernel(const int* __restrict__ bucketCount, int* __restrict__ bucketBase,
                                   int* __restrict__ rs, int n, int e) {
    if (threadIdx.x == 0 && blockIdx.x == 0) {
        int acc = 0;
        for (int i = 0; i < 256; i++) { bucketBase[i] = acc; acc += bucketCount[i]; }
        bucketBase[256] = acc;
        rs[n] = e;
    }
}

// packed entry: (src << 9) | (dst & 511); src < 2^17, N = 100000 fits.
__global__ void bucket_scatter_kernel(const int* __restrict__ src, const int* __restrict__ dst, int e,
                                      const int* __restrict__ bucketBase, const int* __restrict__ blockBase,
                                      unsigned* __restrict__ grouped) {
    __shared__ int cur[256];
    int t = threadIdx.x;
    cur[t] = bucketBase[t] + blockBase[blockIdx.x * 256 + t];
    __syncthreads();
    int base = blockIdx.x * CHUNK;
    #pragma unroll
    for (int k = 0; k < CHUNK / 256; k++) {
        int i = base + k * 256 + t;
        if (i < e) {
            int d = dst[i];
            int pos = atomicAdd(&cur[d >> BKT_SHIFT], 1);
            grouped[pos] = ((unsigned)src[i] << 9) | (unsigned)(d & 511);
        }
    }
}

__global__ void bucket_csr_kernel(const unsigned* __restrict__ grouped, const int* __restrict__ bucketBase,
                                  int* __restrict__ rs, int* __restrict__ csr, int n) {
    __shared__ int sdeg[BKT_NODES];
    __shared__ int sexcl[BKT_NODES];
    __shared__ int wsum[4];
    int b = blockIdx.x;
    int t = threadIdx.x;
    int nodeBase = b << BKT_SHIFT;
    int ebase = bucketBase[b], eend = bucketBase[b + 1];
    sdeg[t] = 0; sdeg[t + 256] = 0;
    __syncthreads();
    for (int e = ebase + t; e < eend; e += 256)
        atomicAdd(&sdeg[grouped[e] & 511u], 1);
    __syncthreads();
    int lane = t & 63, wid = t >> 6;
    int v0 = sdeg[2 * t], v1 = sdeg[2 * t + 1];
    int p = v0 + v1;
    int x = p;
    #pragma unroll
    for (int off = 1; off < 64; off <<= 1) {
        int y = __shfl_up(x, off, 64);
        if (lane >= off) x += y;
    }
    if (lane == 63) wsum[wid] = x;
    __syncthreads();
    if (t == 0) {
        int acc = 0;
        #pragma unroll
        for (int w = 0; w < 4; w++) { int tmp = wsum[w]; wsum[w] = acc; acc += tmp; }
    }
    __syncthreads();
    int basep = wsum[wid] + x - p;
    sexcl[2 * t] = basep;
    sexcl[2 * t + 1] = basep + v0;
    __syncthreads();   // FIX: rs loop below reads sexcl[i] written by OTHER waves (race since r3)
    int nodes = min(BKT_NODES, n - nodeBase);
    for (int i = t; i < nodes; i += 256) rs[nodeBase + i] = ebase + sexcl[i];
    sdeg[t] = 0; sdeg[t + 256] = 0;
    __syncthreads();
    for (int e = ebase + t; e < eend; e += 256) {
        unsigned pr = grouped[e];
        int l = (int)(pr & 511u);
        int r = atomicAdd(&sdeg[l], 1);
        csr[ebase + sexcl[l] + r] = (int)(pr >> 9);
    }
}

// ---------------- Weight prep: Btg[layer][col][k] bf16, ALL pre-scaled by 1/64 ----------------

__global__ void prep_w_kernel(const float* __restrict__ Wl, const float* __restrict__ Wr,
                              ushort* __restrict__ Btg) {
    int idx = blockIdx.x * 256 + threadIdx.x;   // 2*128*256 = 65536
    if (idx >= 65536) return;
    int l = idx >> 15;
    int col = (idx >> 8) & 127;
    int k = idx & 255;
    float v = (k < 128) ? Wl[l * H * H + k * H + col] : Wr[l * H * H + (k - 128) * H + col];
    Btg[idx] = f2b(v * FP8_INV);
}

// ---------------- Layer 0 fused: agg0 (scalar gather) + expand -> fp8 rows ----------------

__global__ void layer0_kernel(const float* __restrict__ x, const int* __restrict__ rs,
                              const int* __restrict__ csr,
                              const float* __restrict__ Wl0, const float* __restrict__ bl0,
                              const float* __restrict__ Wr0,
                              unsigned char* __restrict__ h8, int n) {
    __shared__ float sagg[256], sx[256];
    int base = blockIdx.x * 256;
    int t = threadIdx.x;
    int node = base + t;
    if (node < n) {
        int a = rs[node], b = rs[node + 1];
        float s = 0.f;
        int e = a;
        for (; e + 4 <= b; e += 4)
            s += x[csr[e]] + x[csr[e + 1]] + x[csr[e + 2]] + x[csr[e + 3]];
        for (; e < b; e++) s += x[csr[e]];
        sagg[t] = s / (float)max(b - a, 1);
        sx[t] = x[node];
    }
    __syncthreads();
    int nodes = min(256, n - base);
    #pragma unroll
    for (int pass = 0; pass < 4; pass++) {
        int nl = pass * 64 + (t >> 2);
        int p = t & 3;
        if (nl < nodes) {
            float gi = sagg[nl], xi = sx[nl];
            float v[32];
            #pragma unroll
            for (int k = 0; k < 32; k++) {
                int f = p * 32 + k;
                v[k] = fmaxf(gi * Wl0[f] + bl0[f] + xi * Wr0[f], 0.f) * FP8_SCALE;
            }
            unsigned up[8];
            #pragma unroll
            for (int d = 0; d < 8; d++) {
                int pk = __builtin_amdgcn_cvt_pk_fp8_f32(v[4 * d], v[4 * d + 1], 0, false);
                pk = __builtin_amdgcn_cvt_pk_fp8_f32(v[4 * d + 2], v[4 * d + 3], pk, true);
                up[d] = (unsigned)pk;
            }
            unsigned char* dst8 = h8 + (size_t)(base + nl) * 128 + p * 32;
            *(uint4*)dst8 = (uint4){up[0], up[1], up[2], up[3]};
            *(uint4*)(dst8 + 16) = (uint4){up[4], up[5], up[6], up[7]};
        }
    }
}

// ---------------- Aggregate fp8 -> fp8 (stay in x64 domain): 2 nodes/wave, 4 slots x 8 x 16B ----------------

__global__ void aggregate8_kernel(const unsigned char* __restrict__ h8, const int* __restrict__ rs,
                                  const int* __restrict__ csr, unsigned char* __restrict__ agg8, int n) {
    int tid = threadIdx.x;
    int w = (tid >> 5) & 1;
    int node = blockIdx.x * 8 + (tid >> 6) * 2 + w;
    if (node >= n) return;
    int sl = (tid >> 3) & 3;
    int fl = tid & 7;
    int a = rs[node], b = rs[node + 1];
    f32x2 s[8];
    #pragma unroll
    for (int j = 0; j < 8; j++) s[j] = (f32x2){0.f, 0.f};

    int e = a;
    for (; e + 8 <= b; e += 8) {
        int n0 = csr[e + sl], n1 = csr[e + 4 + sl];
        uint4 u0 = *(const uint4*)(h8 + (size_t)n0 * 128 + 16 * fl);
        uint4 u1 = *(const uint4*)(h8 + (size_t)n1 * 128 + 16 * fl);
        unsigned dw[8] = {u0.x, u0.y, u0.z, u0.w, u1.x, u1.y, u1.z, u1.w};
        #pragma unroll
        for (int d = 0; d < 8; d++) {
            s[(d & 3) * 2]     += __builtin_amdgcn_cvt_pk_f32_fp8(dw[d], false);
            s[(d & 3) * 2 + 1] += __builtin_amdgcn_cvt_pk_f32_fp8(dw[d], true);
        }
    }
    for (; e + 4 <= b; e += 4) {
        int n0 = csr[e + sl];
        uint4 u0 = *(const uint4*)(h8 + (size_t)n0 * 128 + 16 * fl);
        unsigned dw[4] = {u0.x, u0.y, u0.z, u0.w};
        #pragma unroll
        for (int d = 0; d < 4; d++) {
            s[d * 2]     += __builtin_amdgcn_cvt_pk_f32_fp8(dw[d], false);
            s[d * 2 + 1] += __builtin_amdgcn_cvt_pk_f32_fp8(dw[d], true);
        }
    }
    if (e < b && sl < (b - e)) {
        int n0 = csr[e + sl];
        uint4 u0 = *(const uint4*)(h8 + (size_t)n0 * 128 + 16 * fl);
        unsigned dw[4] = {u0.x, u0.y, u0.z, u0.w};
        #pragma unroll
        for (int d = 0; d < 4; d++) {
            s[d * 2]     += __builtin_amdgcn_cvt_pk_f32_fp8(dw[d], false);
            s[d * 2 + 1] += __builtin_amdgcn_cvt_pk_f32_fp8(dw[d], true);
        }
    }
    #pragma unroll
    for (int j = 0; j < 8; j++) {
        s[j].x += __shfl_xor(s[j].x, 8, 64);
        s[j].y += __shfl_xor(s[j].y, 8, 64);
        s[j].x += __shfl_xor(s[j].x, 16, 64);
        s[j].y += __shfl_xor(s[j].y, 16, 64);
    }
    if (sl == 0) {
        float inv = 1.f / (float)max(b - a, 1);   // stays in x64 fp8 domain
        unsigned up[4];
        #pragma unroll
        for (int d = 0; d < 4; d++) {
            int pk = __builtin_amdgcn_cvt_pk_fp8_f32(s[2 * d].x * inv, s[2 * d].y * inv, 0, false);
            pk = __builtin_amdgcn_cvt_pk_fp8_f32(s[2 * d + 1].x * inv, s[2 * d + 1].y * inv, pk, true);
            up[d] = (unsigned)pk;
        }
        *(uint4*)(agg8 + (size_t)node * 128 + 16 * fl) = (uint4){up[0], up[1], up[2], up[3]};
    }
}

// ---------------- Fused dual GEMM: A = [agg8 | h8] fp8->bf16 in-reg, B (x 1/64) in registers ----------------

template<bool POOL>
__global__ __launch_bounds__(256, 2) void gemm_kernel(
    const unsigned char* __restrict__ agg8, const unsigned char* __restrict__ h8,
    const ushort* __restrict__ Btg,   // [128][256] bf16 for this layer, pre-scaled 1/64
    const float* __restrict__ bias,
    unsigned char* __restrict__ out8,
    float* __restrict__ partial, int nblk, int n) {
    __shared__ float sums[2][128];
    int tid = threadIdx.x;
    int wave = tid >> 6, lane = tid & 63;
    int l15 = lane & 15, lhi = lane >> 4;
    int colhalf = wave & 1;
    int rowsub = wave >> 1;
    int colbase = colhalf * 64;

    short8 bf[4][8];
    #pragma unroll
    for (int c2 = 0; c2 < 4; c2++) {
        const ushort* wp = Btg + (colbase + c2 * 16 + l15) * 256 + lhi * 8;
        #pragma unroll
        for (int s = 0; s < 8; s++)
            bf[c2][s] = *(const short8*)(wp + s * 32);
    }
    f32x4 bias_v[4];
    #pragma unroll
    for (int c2 = 0; c2 < 4; c2++)
        bias_v[c2] = *(const f32x4*)(bias + colbase + c2 * 16 + lhi * 4);

    f32x4 fs[4];
    #pragma unroll
    for (int c2 = 0; c2 < 4; c2++) fs[c2] = (f32x4){0.f, 0.f, 0.f, 0.f};

    for (int r0 = blockIdx.x * 32; r0 < n; r0 += nblk * 32) {
        int row = r0 + rowsub * 16 + l15;
        int arow = min(row, n - 1);
        const unsigned char* ar8 = agg8 + (size_t)arow * 128 + lhi * 8;
        const unsigned char* hr8 = h8 + (size_t)arow * 128 + lhi * 8;
        short8 af[8];
        #pragma unroll
        for (int s = 0; s < 8; s++) {
            uint2 u = *(const uint2*)((s < 4 ? ar8 : hr8) + (s & 3) * 32);
            f32x2 a0 = __builtin_amdgcn_cvt_pk_f32_fp8(u.x, false);
            f32x2 a1 = __builtin_amdgcn_cvt_pk_f32_fp8(u.x, true);
            f32x2 a2 = __builtin_amdgcn_cvt_pk_f32_fp8(u.y, false);
            f32x2 a3 = __builtin_amdgcn_cvt_pk_f32_fp8(u.y, true);
            unsigned d0 = __builtin_amdgcn_perm(__builtin_bit_cast(unsigned, a0.y), __builtin_bit_cast(unsigned, a0.x), 0x07060302u);
            unsigned d1 = __builtin_amdgcn_perm(__builtin_bit_cast(unsigned, a1.y), __builtin_bit_cast(unsigned, a1.x), 0x07060302u);
            unsigned d2 = __builtin_amdgcn_perm(__builtin_bit_cast(unsigned, a2.y), __builtin_bit_cast(unsigned, a2.x), 0x07060302u);
            unsigned d3 = __builtin_amdgcn_perm(__builtin_bit_cast(unsigned, a3.y), __builtin_bit_cast(unsigned, a3.x), 0x07060302u);
            union { unsigned u4[4]; short8 s8; } pk;
            pk.u4[0] = d0; pk.u4[1] = d1; pk.u4[2] = d2; pk.u4[3] = d3;
            af[s] = pk.s8;
        }
        f32x4 acc[4];
        #pragma unroll
        for (int c2 = 0; c2 < 4; c2++) acc[c2] = (f32x4){0.f, 0.f, 0.f, 0.f};
        #pragma unroll
        for (int s = 0; s < 8; s++) {
            #pragma unroll
            for (int c2 = 0; c2 < 4; c2++)
                acc[c2] = __builtin_amdgcn_mfma_f32_16x16x32_bf16(bf[c2][s], af[s], acc[c2], 0, 0, 0);
        }
        if (row < n) {
            if (POOL) {
                #pragma unroll
                for (int c2 = 0; c2 < 4; c2++)
                    #pragma unroll
                    for (int r = 0; r < 4; r++)
                        fs[c2][r] += fmaxf(acc[c2][r] + bias_v[c2][r], 0.f);
            } else {
                #pragma unroll
                for (int c2 = 0; c2 < 4; c2++) {
                    float v0 = fmaxf(acc[c2][0] + bias_v[c2][0], 0.f) * FP8_SCALE;
                    float v1 = fmaxf(acc[c2][1] + bias_v[c2][1], 0.f) * FP8_SCALE;
                    float v2 = fmaxf(acc[c2][2] + bias_v[c2][2], 0.f) * FP8_SCALE;
                    float v3 = fmaxf(acc[c2][3] + bias_v[c2][3], 0.f) * FP8_SCALE;
                    int pk = __builtin_amdgcn_cvt_pk_fp8_f32(v0, v1, 0, false);
                    pk = __builtin_amdgcn_cvt_pk_fp8_f32(v2, v3, pk, true);
                    *(unsigned*)(out8 + (size_t)row * 128 + colbase + c2 * 16 + lhi * 4) = (unsigned)pk;
                }
            }
        }
    }

    if (POOL) {
        #pragma unroll
        for (int c2 = 0; c2 < 4; c2++) {
            #pragma unroll
            for (int m = 1; m < 16; m <<= 1) {
                #pragma unroll
                for (int r = 0; r < 4; r++)
                    fs[c2][r] += __shfl_xor(fs[c2][r], m, 64);
            }
        }
        if (l15 == 0) {
            #pragma unroll
            for (int c2 = 0; c2 < 4; c2++)
                #pragma unroll
                for (int r = 0; r < 4; r++)
                    sums[rowsub][colbase + c2 * 16 + lhi * 4 + r] = fs[c2][r];
        }
        __syncthreads();
        if (tid < 128)
            partial[(size_t)tid * nblk + blockIdx.x] = sums[0][tid] + sums[1][tid];  // transposed
    }
}

// ---------------- Final pooling reduce: one wave per feature, contiguous row ----------------

__global__ void pool_reduce_kernel(const float* __restrict__ partial, float* __restrict__ pooled,
                                   int nb, float invn) {
    int j = blockIdx.x;      // feature
    int t = threadIdx.x;     // 64 (one wave)
    float s = 0.f;
    for (int b = t; b < nb; b += 64) s += partial[(size_t)j * nb + b];
    #pragma unroll
    for (int off = 32; off > 0; off >>= 1) s += __shfl_down(s, off, 64);
    if (t == 0) pooled[j] = s * invn;
}

// ---------------- Final MLP ----------------

__global__ void mlp_kernel(const float* __restrict__ pooled,
                           const float* __restrict__ Wv, const float* __restrict__ bv,
                           const float* __restrict__ temp, const float* __restrict__ tt,
                           const float* __restrict__ Wm1, const float* __restrict__ bm1,
                           const float* __restrict__ Wm2, const float* __restrict__ bm2,
                           float* __restrict__ out) {
    __shared__ float feat[66];
    __shared__ float red[2];
    int j = threadIdx.x;  // 128 threads
    if (j < 64) {
        float s = bv[j];
        for (int k = 0; k < H; k++) s += pooled[k] * Wv[k * 64 + j];
        feat[j] = s;
    }
    if (j == 64) feat[64] = temp[0];
    if (j == 65) feat[65] = tt[0];
    __syncthreads();
    float m = bm1[j];
    for (int k = 0; k < 66; k++) m += feat[k] * Wm1[k * H + j];
    m = fmaxf(m, 0.f);
    float p = m * Wm2[j];
    #pragma unroll
    for (int off = 32; off > 0; off >>= 1) p += __shfl_down(p, off, 64);
    if ((j & 63) == 0) red[j >> 6] = p;
    __syncthreads();
    if (j == 0) {
        float x = red[0] + red[1] + bm2[0];
        out[0] = (x > 20.f) ? x : log1pf(expf(x));
    }
}

// ---------------- Launch ----------------

extern "C" void kernel_launch(void* const* d_in, const int* in_sizes, int n_in,
                              void* d_out, int out_size, void* d_ws, size_t ws_size,
                              hipStream_t stream) {
    const float* node_feats = (const float*)d_in[0];
    const int* edge_index = (const int*)d_in[1];
    const float* temp = (const float*)d_in[3];
    const float* tt   = (const float*)d_in[4];
    const float* Wl0 = (const float*)d_in[5];
    const float* bl0 = (const float*)d_in[6];
    const float* Wr0 = (const float*)d_in[7];
    const float* Wl  = (const float*)d_in[8];
    const float* bl  = (const float*)d_in[9];
    const float* Wr  = (const float*)d_in[10];
    const float* Wv  = (const float*)d_in[11];
    const float* bv  = (const float*)d_in[12];
    const float* Wm1 = (const float*)d_in[13];
    const float* bm1 = (const float*)d_in[14];
    const float* Wm2 = (const float*)d_in[15];
    const float* bm2 = (const float*)d_in[16];

    const int N = in_sizes[0];
    const int E = in_sizes[1] / 2;
    const int* src = edge_index;
    const int* dst = edge_index + E;

    size_t NB8 = (size_t)N * 128;                     // bytes per fp8 array
    unsigned char* agg8 = (unsigned char*)d_ws;       // N*128 fp8
    ushort* Btg  = (ushort*)(agg8 + NB8);             // 2*128*256 bf16
    unsigned char* hA8 = (unsigned char*)(Btg + 65536);  // N*128 fp8
    unsigned char* hB8 = hA8 + NB8;                   // N*128 fp8
    unsigned* grouped = (unsigned*)(hB8 + NB8);       // E packed
    int* csr     = (int*)(grouped + E);               // E
    int* rs      = csr + E;                           // N+1
    int* bucketCount = rs + (N + 1);                  // 256
    int* bucketBase  = bucketCount + 256;             // 257
    int* blockBase   = bucketBase + 257;              // NBLK*256
    int NBLK = (E + CHUNK - 1) / CHUNK;
    float* partial = (float*)(blockBase + NBLK * 256);  // 128*GEMM_GRID (transposed)
    float* pooled  = partial + (size_t)H * GEMM_GRID;   // H

    int NB = (N + BKT_NODES - 1) / BKT_NODES;

    // CSR build (bucketed, packed)
    hipMemsetAsync(bucketCount, 0, 256 * sizeof(int), stream);
    bucket_hist_kernel<<<NBLK, 256, 0, stream>>>(dst, E, bucketCount, blockBase);
    bucket_scan_kernel<<<1, 64, 0, stream>>>(bucketCount, bucketBase, rs, N, E);
    bucket_scatter_kernel<<<NBLK, 256, 0, stream>>>(src, dst, E, bucketBase, blockBase, grouped);
    bucket_csr_kernel<<<NB, 256, 0, stream>>>(grouped, bucketBase, rs, csr, N);

    // Weights -> bf16 transposed [layer][col][k], pre-scaled 1/64
    prep_w_kernel<<<256, 256, 0, stream>>>(Wl, Wr, Btg);

    // Layer 0 fused: agg0 + expand -> hA8 (fp8 rows)
    layer0_kernel<<<(N + 255) / 256, 256, 0, stream>>>(node_feats, rs, csr, Wl0, bl0, Wr0, hA8, N);

    // Layer 1: fp8 gather-mean -> agg8; gemm -> hB8
    aggregate8_kernel<<<(N + 7) / 8, 256, 0, stream>>>(hA8, rs, csr, agg8, N);
    gemm_kernel<false><<<GEMM_GRID, 256, 0, stream>>>(agg8, hA8, Btg, bl, hB8, nullptr, GEMM_GRID, N);

    // Layer 2: fp8 gather-mean -> agg8; gemm (fused pooling)
    aggregate8_kernel<<<(N + 7) / 8, 256, 0, stream>>>(hB8, rs, csr, agg8, N);
    gemm_kernel<true><<<GEMM_GRID, 256, 0, stream>>>(agg8, hB8, Btg + 32768, bl + H, nullptr, partial, GEMM_GRID, N);

    // Final pooling reduce + MLP
    pool_reduce_kernel<<<H, 64, 0, stream>>>(partial, pooled, GEMM_GRID, 1.0f / (float)N);
    mlp_kernel<<<1, H, 0, stream>>>(pooled, Wv, bv, temp, tt, Wm1, bm1, Wm2, bm2, (float*)d_out);
}